// Round 1
// baseline (1412.589 us; speedup 1.0000x reference)
//
#include <hip/hip_runtime.h>
#include <cfloat>
#include <cmath>

#define LEAKY 0.2f

// float atomic max via monotone int mapping:
// non-negative floats are ordered as signed ints; negative floats reverse-ordered as unsigned.
__device__ __forceinline__ void atomicMaxF(float* addr, float v) {
    if (v >= 0.0f) atomicMax((int*)addr, __float_as_int(v));
    else           atomicMin((unsigned int*)addr, (unsigned int)__float_as_int(v));
}

// ---------------- init: zero accumulators, -inf maxes, out = b2 ----------------
__global__ void init_k(float* __restrict__ out1, float* __restrict__ m1, float* __restrict__ s1,
                       float* __restrict__ m2, float* __restrict__ s2,
                       float* __restrict__ dout, const float* __restrict__ b2, int Nn) {
    int i = blockIdx.x * 256 + threadIdx.x;
    if (i >= Nn * 128) return;
    out1[i] = 0.0f;
    if (i < Nn * 4)  { m1[i] = -FLT_MAX; s1[i] = 0.0f; }
    if (i < Nn)      { m2[i] = -FLT_MAX; s2[i] = 0.0f; }
    if (i < Nn * 16) dout[i] = b2[i & 15];
}

// ---------------- layer1 GEMM: h1[N,128] = x[N,256] @ W1[256,128] ----------------
__global__ __launch_bounds__(128) void gemm1_k(const float* __restrict__ x,
                                               const float* __restrict__ W,
                                               float* __restrict__ h1) {
    __shared__ float xs[16][256];
    const int j = threadIdx.x;            // output column 0..127
    const int rowBase = blockIdx.x * 16;
    for (int idx = j; idx < 16 * 256; idx += 128) {
        int r = idx >> 8, c = idx & 255;
        xs[r][c] = x[(size_t)(rowBase + r) * 256 + c];
    }
    __syncthreads();
    float acc[16];
#pragma unroll
    for (int r = 0; r < 16; ++r) acc[r] = 0.0f;
    for (int k = 0; k < 256; ++k) {
        float w = W[k * 128 + j];
#pragma unroll
        for (int r = 0; r < 16; ++r) acc[r] += xs[r][k] * w;
    }
#pragma unroll
    for (int r = 0; r < 16; ++r)
        h1[(size_t)(rowBase + r) * 128 + j] = acc[r];
}

// ---------------- layer1 attention coefficients a_src/a_dst [N,4] ----------------
__global__ void acoef1_k(const float* __restrict__ h1, const float* __restrict__ att_s,
                         const float* __restrict__ att_d, float* __restrict__ a1s,
                         float* __restrict__ a1d, int Nn) {
    int g = blockIdx.x * 256 + threadIdx.x;
    if (g >= Nn * 4) return;
    int node = g >> 2, head = g & 3;
    const float* hp = h1 + (size_t)node * 128 + head * 32;
    float s = 0.0f, d = 0.0f;
#pragma unroll
    for (int c = 0; c < 32; ++c) {
        float v = hp[c];
        s += v * att_s[head * 32 + c];
        d += v * att_d[head * 32 + c];
    }
    a1s[g] = s; a1d[g] = d;
}

// ---------------- layer1 edge passes ----------------
__device__ __forceinline__ void edge_sd(const int* __restrict__ ei, int e, int E, int& s, int& d) {
    if (e < E) { s = ei[e]; d = ei[E + e]; }
    else       { s = e - E; d = e - E; }
}

__global__ void emax1_k(const int* __restrict__ ei, int E, int ET,
                        const float* __restrict__ a1s, const float* __restrict__ a1d,
                        float* __restrict__ m1) {
    int g = blockIdx.x * 256 + threadIdx.x;
    if (g >= ET * 4) return;
    int e = g >> 2, head = g & 3;
    int s, d; edge_sd(ei, e, E, s, d);
    float v = a1s[s * 4 + head] + a1d[d * 4 + head];
    v = v >= 0.0f ? v : LEAKY * v;
    atomicMaxF(&m1[d * 4 + head], v);
}

__global__ void esum1_k(const int* __restrict__ ei, int E, int ET,
                        const float* __restrict__ a1s, const float* __restrict__ a1d,
                        const float* __restrict__ m1, float* __restrict__ s1) {
    int g = blockIdx.x * 256 + threadIdx.x;
    if (g >= ET * 4) return;
    int e = g >> 2, head = g & 3;
    int s, d; edge_sd(ei, e, E, s, d);
    float v = a1s[s * 4 + head] + a1d[d * 4 + head];
    v = v >= 0.0f ? v : LEAKY * v;
    atomicAdd(&s1[d * 4 + head], expf(v - m1[d * 4 + head]));
}

__global__ void eagg1_k(const int* __restrict__ ei, int E, int ET,
                        const float* __restrict__ a1s, const float* __restrict__ a1d,
                        const float* __restrict__ m1, const float* __restrict__ s1,
                        const float* __restrict__ h1, float* __restrict__ out1) {
    unsigned int g = blockIdx.x * 256u + threadIdx.x;
    if (g >= (unsigned int)ET * 128u) return;
    int e = g >> 7, j = g & 127, head = j >> 5;
    int s, d; edge_sd(ei, e, E, s, d);
    float v = a1s[s * 4 + head] + a1d[d * 4 + head];
    v = v >= 0.0f ? v : LEAKY * v;
    float alpha = expf(v - m1[d * 4 + head]) / (s1[d * 4 + head] + 1e-16f);
    atomicAdd(&out1[(size_t)d * 128 + j], h1[(size_t)s * 128 + j] * alpha);
}

// ---------------- ELU(out1 + b1) in place ----------------
__global__ void elu_k(float* __restrict__ out1, const float* __restrict__ b1, int tot) {
    int i = blockIdx.x * 256 + threadIdx.x;
    if (i >= tot) return;
    float v = out1[i] + b1[i & 127];
    out1[i] = v > 0.0f ? v : expm1f(v);
}

// ---------------- layer2 GEMM + attention coefficients ----------------
__global__ __launch_bounds__(256) void gemm2_k(const float* __restrict__ hin,
                                               const float* __restrict__ W2,
                                               const float* __restrict__ att_s2,
                                               const float* __restrict__ att_d2,
                                               float* __restrict__ h2,
                                               float* __restrict__ a2s, float* __restrict__ a2d) {
    __shared__ float hs[16][129];   // +1 pad: 16 ln-rows hit distinct banks
    __shared__ float w2s[128 * 16];
    const int t = threadIdx.x;
    const int nodeBase = blockIdx.x * 16;
    for (int idx = t; idx < 16 * 128; idx += 256) {
        hs[idx >> 7][idx & 127] = hin[(size_t)nodeBase * 128 + idx];
        w2s[idx] = W2[idx];
    }
    __syncthreads();
    const int ln = t >> 4, j = t & 15;
    float acc = 0.0f;
    for (int k = 0; k < 128; ++k) acc += hs[ln][k] * w2s[k * 16 + j];
    const int node = nodeBase + ln;
    h2[(size_t)node * 16 + j] = acc;
    float vs = acc * att_s2[j];
    float vd = acc * att_d2[j];
#pragma unroll
    for (int off = 8; off; off >>= 1) {
        vs += __shfl_xor(vs, off);
        vd += __shfl_xor(vd, off);
    }
    if (j == 0) { a2s[node] = vs; a2d[node] = vd; }
}

// ---------------- layer2 edge passes (H=1, C=16) ----------------
__global__ void emax2_k(const int* __restrict__ ei, int E, int ET,
                        const float* __restrict__ a2s, const float* __restrict__ a2d,
                        float* __restrict__ m2) {
    int e = blockIdx.x * 256 + threadIdx.x;
    if (e >= ET) return;
    int s, d; edge_sd(ei, e, E, s, d);
    float v = a2s[s] + a2d[d];
    v = v >= 0.0f ? v : LEAKY * v;
    atomicMaxF(&m2[d], v);
}

__global__ void esum2_k(const int* __restrict__ ei, int E, int ET,
                        const float* __restrict__ a2s, const float* __restrict__ a2d,
                        const float* __restrict__ m2, float* __restrict__ s2) {
    int e = blockIdx.x * 256 + threadIdx.x;
    if (e >= ET) return;
    int s, d; edge_sd(ei, e, E, s, d);
    float v = a2s[s] + a2d[d];
    v = v >= 0.0f ? v : LEAKY * v;
    atomicAdd(&s2[d], expf(v - m2[d]));
}

__global__ void eagg2_k(const int* __restrict__ ei, int E, int ET,
                        const float* __restrict__ a2s, const float* __restrict__ a2d,
                        const float* __restrict__ m2, const float* __restrict__ s2,
                        const float* __restrict__ h2, float* __restrict__ dout) {
    unsigned int g = blockIdx.x * 256u + threadIdx.x;
    if (g >= (unsigned int)ET * 16u) return;
    int e = g >> 4, j = g & 15;
    int s, d; edge_sd(ei, e, E, s, d);
    float v = a2s[s] + a2d[d];
    v = v >= 0.0f ? v : LEAKY * v;
    float alpha = expf(v - m2[d]) / (s2[d] + 1e-16f);
    atomicAdd(&dout[(size_t)d * 16 + j], h2[(size_t)s * 16 + j] * alpha);
}

extern "C" void kernel_launch(void* const* d_in, const int* in_sizes, int n_in,
                              void* d_out, int out_size, void* d_ws, size_t ws_size,
                              hipStream_t stream) {
    const float* x    = (const float*)d_in[0];
    const int*   ei   = (const int*)d_in[1];
    const float* W1   = (const float*)d_in[2];
    const float* att_s1 = (const float*)d_in[3];
    const float* att_d1 = (const float*)d_in[4];
    const float* b1   = (const float*)d_in[5];
    const float* W2   = (const float*)d_in[6];
    const float* att_s2 = (const float*)d_in[7];
    const float* att_d2 = (const float*)d_in[8];
    const float* b2   = (const float*)d_in[9];
    float* dout = (float*)d_out;

    const int Nn = in_sizes[0] / 256;     // 100000
    const int E  = in_sizes[1] / 2;       // 1600000
    const int ET = E + Nn;                // + self loops

    float* ws = (float*)d_ws;
    size_t o = 0;
    float* h1   = ws + o; o += (size_t)Nn * 128;
    float* out1 = ws + o; o += (size_t)Nn * 128;
    float* h2   = ws + o; o += (size_t)Nn * 16;
    float* a1s  = ws + o; o += (size_t)Nn * 4;
    float* a1d  = ws + o; o += (size_t)Nn * 4;
    float* m1   = ws + o; o += (size_t)Nn * 4;
    float* s1   = ws + o; o += (size_t)Nn * 4;
    float* a2s  = ws + o; o += (size_t)Nn;
    float* a2d  = ws + o; o += (size_t)Nn;
    float* m2   = ws + o; o += (size_t)Nn;
    float* s2   = ws + o; o += (size_t)Nn;

    dim3 blk(256);

    // init
    init_k<<<dim3((Nn * 128 + 255) / 256), blk, 0, stream>>>(out1, m1, s1, m2, s2, dout, b2, Nn);
    // layer 1
    gemm1_k<<<dim3(Nn / 16), dim3(128), 0, stream>>>(x, W1, h1);
    acoef1_k<<<dim3((Nn * 4 + 255) / 256), blk, 0, stream>>>(h1, att_s1, att_d1, a1s, a1d, Nn);
    emax1_k<<<dim3((ET * 4 + 255) / 256), blk, 0, stream>>>(ei, E, ET, a1s, a1d, m1);
    esum1_k<<<dim3((ET * 4 + 255) / 256), blk, 0, stream>>>(ei, E, ET, a1s, a1d, m1, s1);
    {
        unsigned int tot = (unsigned int)ET * 128u;
        eagg1_k<<<dim3((tot + 255u) / 256u), blk, 0, stream>>>(ei, E, ET, a1s, a1d, m1, s1, h1, out1);
    }
    elu_k<<<dim3((Nn * 128 + 255) / 256), blk, 0, stream>>>(out1, b1, Nn * 128);
    // layer 2
    gemm2_k<<<dim3(Nn / 16), blk, 0, stream>>>(out1, W2, att_s2, att_d2, h2, a2s, a2d);
    emax2_k<<<dim3((ET + 255) / 256), blk, 0, stream>>>(ei, E, ET, a2s, a2d, m2);
    esum2_k<<<dim3((ET + 255) / 256), blk, 0, stream>>>(ei, E, ET, a2s, a2d, m2, s2);
    {
        unsigned int tot = (unsigned int)ET * 16u;
        eagg2_k<<<dim3((tot + 255u) / 256u), blk, 0, stream>>>(ei, E, ET, a2s, a2d, m2, s2, h2, dout);
    }
}

// Round 2
// 635.781 us; speedup vs baseline: 2.2218x; 2.2218x over previous
//
#include <hip/hip_runtime.h>
#include <cfloat>
#include <cmath>

#define LEAKY 0.2f

// ---------------- init: zero CSR counters ----------------
__global__ void init_k(int* __restrict__ cnt, int* __restrict__ cnt2, int Nn) {
    int i = blockIdx.x * 256 + threadIdx.x;
    if (i < Nn) { cnt[i] = 0; cnt2[i] = 0; }
}

__device__ __forceinline__ void edge_sd(const int* __restrict__ ei, int e, int E, int& s, int& d) {
    if (e < E) { s = ei[e]; d = ei[E + e]; }
    else       { s = e - E; d = e - E; }   // self loops appended
}

// ---------------- CSR build: histogram, scan, scatter ----------------
__global__ void hist_k(const int* __restrict__ ei, int E, int ET, int* __restrict__ cnt) {
    int e = blockIdx.x * 256 + threadIdx.x;
    if (e >= ET) return;
    int s, d; edge_sd(ei, e, E, s, d);
    atomicAdd(&cnt[d], 1);
}

__global__ __launch_bounds__(1024) void scan_blk_k(const int* __restrict__ cnt,
                                                   int* __restrict__ rowptr,
                                                   int* __restrict__ part, int Nn) {
    __shared__ int sm[1024];
    int t = threadIdx.x, i = blockIdx.x * 1024 + t;
    int v = (i < Nn) ? cnt[i] : 0;
    sm[t] = v; __syncthreads();
    for (int off = 1; off < 1024; off <<= 1) {
        int add = (t >= off) ? sm[t - off] : 0;
        __syncthreads();
        sm[t] += add;
        __syncthreads();
    }
    if (i < Nn) rowptr[i] = sm[t] - v;          // exclusive within block
    if (t == 1023) part[blockIdx.x] = sm[1023]; // block total
}

__global__ __launch_bounds__(128) void scan_part_k(int* __restrict__ part, int nb) {
    __shared__ int sm[128];
    int t = threadIdx.x;
    int v = (t < nb) ? part[t] : 0;
    sm[t] = v; __syncthreads();
    for (int off = 1; off < 128; off <<= 1) {
        int add = (t >= off) ? sm[t - off] : 0;
        __syncthreads();
        sm[t] += add;
        __syncthreads();
    }
    if (t < nb) part[t] = sm[t] - v;            // exclusive
}

__global__ __launch_bounds__(1024) void scan_add_k(int* __restrict__ rowptr,
                                                   const int* __restrict__ part,
                                                   int Nn, int ET) {
    int i = blockIdx.x * 1024 + threadIdx.x;
    if (i < Nn) rowptr[i] += part[blockIdx.x];
    if (i == 0) rowptr[Nn] = ET;
}

__global__ void scatter_k(const int* __restrict__ ei, int E, int ET,
                          const int* __restrict__ rowptr, int* __restrict__ cnt2,
                          int* __restrict__ srcs) {
    int e = blockIdx.x * 256 + threadIdx.x;
    if (e >= ET) return;
    int s, d; edge_sd(ei, e, E, s, d);
    int pos = rowptr[d] + atomicAdd(&cnt2[d], 1);
    srcs[pos] = s;
}

// ---------------- layer1 GEMM: h1[N,128] = x[N,256] @ W1[256,128] ----------------
__global__ __launch_bounds__(128) void gemm1_k(const float* __restrict__ x,
                                               const float* __restrict__ W,
                                               float* __restrict__ h1) {
    __shared__ float xs[16][256];
    const int j = threadIdx.x;
    const int rowBase = blockIdx.x * 16;
    for (int idx = j; idx < 16 * 256; idx += 128) {
        int r = idx >> 8, c = idx & 255;
        xs[r][c] = x[(size_t)(rowBase + r) * 256 + c];
    }
    __syncthreads();
    float acc[16];
#pragma unroll
    for (int r = 0; r < 16; ++r) acc[r] = 0.0f;
    for (int k = 0; k < 256; ++k) {
        float w = W[k * 128 + j];
#pragma unroll
        for (int r = 0; r < 16; ++r) acc[r] += xs[r][k] * w;
    }
#pragma unroll
    for (int r = 0; r < 16; ++r)
        h1[(size_t)(rowBase + r) * 128 + j] = acc[r];
}

// ---------------- layer1 attention coefficients [N,4] ----------------
__global__ void acoef1_k(const float* __restrict__ h1, const float* __restrict__ att_s,
                         const float* __restrict__ att_d, float* __restrict__ a1s,
                         float* __restrict__ a1d, int Nn) {
    int g = blockIdx.x * 256 + threadIdx.x;
    if (g >= Nn * 4) return;
    int node = g >> 2, head = g & 3;
    const float4* hp = (const float4*)(h1 + (size_t)node * 128 + head * 32);
    const float4* as = (const float4*)(att_s + head * 32);
    const float4* ad = (const float4*)(att_d + head * 32);
    float s = 0.0f, d = 0.0f;
#pragma unroll
    for (int c = 0; c < 8; ++c) {
        float4 v = hp[c], a = as[c], b = ad[c];
        s += v.x * a.x + v.y * a.y + v.z * a.z + v.w * a.w;
        d += v.x * b.x + v.y * b.y + v.z * b.z + v.w * b.w;
    }
    a1s[g] = s; a1d[g] = d;
}

// ---------------- layer1 fused segment softmax + aggregate + bias + ELU ----------------
// one 64-lane wave per destination node
__global__ __launch_bounds__(256) void agg1_k(const int* __restrict__ rowptr,
                                              const int* __restrict__ srcs,
                                              const float* __restrict__ a1s,
                                              const float* __restrict__ a1d,
                                              const float* __restrict__ h1,
                                              const float* __restrict__ b1,
                                              float* __restrict__ out1, int Nn) {
    int wid = (blockIdx.x * 256 + threadIdx.x) >> 6;
    int lane = threadIdx.x & 63;
    if (wid >= Nn) return;
    const int n = wid;
    const int beg = rowptr[n], end = rowptr[n + 1];
    const int h = lane & 3, eg = lane >> 2;      // 16 edge-groups x 4 heads
    const float a1dn = a1d[n * 4 + h];
    // pass 1: per-head max
    float m = -FLT_MAX;
    for (int k = beg + eg; k < end; k += 16) {
        int s = srcs[k];
        float v = a1s[s * 4 + h] + a1dn;
        v = fmaxf(v, LEAKY * v);                 // leaky_relu, slope<1
        m = fmaxf(m, v);
    }
#pragma unroll
    for (int off = 4; off < 64; off <<= 1) m = fmaxf(m, __shfl_xor(m, off));
    // pass 2: per-head sum of exp
    float ss = 0.0f;
    for (int k = beg + eg; k < end; k += 16) {
        int s = srcs[k];
        float v = a1s[s * 4 + h] + a1dn;
        v = fmaxf(v, LEAKY * v);
        ss += __expf(v - m);
    }
#pragma unroll
    for (int off = 4; off < 64; off <<= 1) ss += __shfl_xor(ss, off);
    const float sinv = 1.0f / (ss + 1e-16f);
    // pass 3: weighted aggregation, lane owns cols {2*lane, 2*lane+1}, head hc=lane>>4
    const int hc = lane >> 4;
    const float mC = __shfl(m, hc);              // lane hc holds head hc's stats
    const float siC = __shfl(sinv, hc);
    const float adC = __shfl(a1dn, hc);
    float2 acc = make_float2(0.0f, 0.0f);
    const int cntE = end - beg;
    int sv = (beg + lane < end) ? srcs[beg + lane] : 0;   // 64-edge window in regs
    for (int ko = 0; ko < cntE; ++ko) {
        if (ko && (ko & 63) == 0)
            sv = (beg + ko + lane < end) ? srcs[beg + ko + lane] : 0;
        int s = __shfl(sv, ko & 63);
        float vv = a1s[s * 4 + hc] + adC;
        vv = fmaxf(vv, LEAKY * vv);
        float al = __expf(vv - mC) * siC;
        float2 hv = *(const float2*)&h1[(size_t)s * 128 + 2 * lane];
        acc.x += al * hv.x; acc.y += al * hv.y;
    }
    float2 bb = *(const float2*)&b1[2 * lane];
    float ox = acc.x + bb.x, oy = acc.y + bb.y;
    ox = ox > 0.0f ? ox : expm1f(ox);            // ELU fused
    oy = oy > 0.0f ? oy : expm1f(oy);
    *(float2*)&out1[(size_t)n * 128 + 2 * lane] = make_float2(ox, oy);
}

// ---------------- layer2 GEMM + attention coefficients ----------------
__global__ __launch_bounds__(256) void gemm2_k(const float* __restrict__ hin,
                                               const float* __restrict__ W2,
                                               const float* __restrict__ att_s2,
                                               const float* __restrict__ att_d2,
                                               float* __restrict__ h2,
                                               float* __restrict__ a2s, float* __restrict__ a2d) {
    __shared__ float hs[16][129];
    __shared__ float w2s[128 * 16];
    const int t = threadIdx.x;
    const int nodeBase = blockIdx.x * 16;
    for (int idx = t; idx < 16 * 128; idx += 256) {
        hs[idx >> 7][idx & 127] = hin[(size_t)nodeBase * 128 + idx];
        w2s[idx] = W2[idx];
    }
    __syncthreads();
    const int ln = t >> 4, j = t & 15;
    float acc = 0.0f;
    for (int k = 0; k < 128; ++k) acc += hs[ln][k] * w2s[k * 16 + j];
    const int node = nodeBase + ln;
    h2[(size_t)node * 16 + j] = acc;
    float vs = acc * att_s2[j];
    float vd = acc * att_d2[j];
#pragma unroll
    for (int off = 8; off; off >>= 1) {
        vs += __shfl_xor(vs, off);
        vd += __shfl_xor(vd, off);
    }
    if (j == 0) { a2s[node] = vs; a2d[node] = vd; }
}

// ---------------- layer2 fused segment softmax + aggregate + bias ----------------
// one 64-lane wave per node; 4 edge-groups x 16 cols
__global__ __launch_bounds__(256) void agg2_k(const int* __restrict__ rowptr,
                                              const int* __restrict__ srcs,
                                              const float* __restrict__ a2s,
                                              const float* __restrict__ a2d,
                                              const float* __restrict__ h2,
                                              const float* __restrict__ b2,
                                              float* __restrict__ dout, int Nn) {
    int wid = (blockIdx.x * 256 + threadIdx.x) >> 6;
    int lane = threadIdx.x & 63;
    if (wid >= Nn) return;
    const int n = wid;
    const int beg = rowptr[n], end = rowptr[n + 1];
    const int eg = lane >> 4, j = lane & 15;
    const float a2dn = a2d[n];
    float m = -FLT_MAX;
    for (int k = beg + eg; k < end; k += 4) {
        float v = a2s[srcs[k]] + a2dn;
        v = fmaxf(v, LEAKY * v);
        m = fmaxf(m, v);
    }
    m = fmaxf(m, __shfl_xor(m, 16));
    m = fmaxf(m, __shfl_xor(m, 32));
    float ss = 0.0f;
    for (int k = beg + eg; k < end; k += 4) {
        float v = a2s[srcs[k]] + a2dn;
        v = fmaxf(v, LEAKY * v);
        ss += __expf(v - m);
    }
    ss += __shfl_xor(ss, 16);
    ss += __shfl_xor(ss, 32);
    const float sinv = 1.0f / (ss + 1e-16f);
    float acc = 0.0f;
    for (int k = beg + eg; k < end; k += 4) {
        int s = srcs[k];
        float v = a2s[s] + a2dn;
        v = fmaxf(v, LEAKY * v);
        float al = __expf(v - m) * sinv;
        acc += al * h2[(size_t)s * 16 + j];
    }
    acc += __shfl_xor(acc, 16);
    acc += __shfl_xor(acc, 32);
    if (lane < 16) dout[(size_t)n * 16 + j] = acc + b2[j];
}

extern "C" void kernel_launch(void* const* d_in, const int* in_sizes, int n_in,
                              void* d_out, int out_size, void* d_ws, size_t ws_size,
                              hipStream_t stream) {
    const float* x      = (const float*)d_in[0];
    const int*   ei     = (const int*)d_in[1];
    const float* W1     = (const float*)d_in[2];
    const float* att_s1 = (const float*)d_in[3];
    const float* att_d1 = (const float*)d_in[4];
    const float* b1     = (const float*)d_in[5];
    const float* W2     = (const float*)d_in[6];
    const float* att_s2 = (const float*)d_in[7];
    const float* att_d2 = (const float*)d_in[8];
    const float* b2     = (const float*)d_in[9];
    float* dout = (float*)d_out;

    const int Nn = in_sizes[0] / 256;     // 100000
    const int E  = in_sizes[1] / 2;       // 1600000
    const int ET = E + Nn;                // + self loops

    float* ws = (float*)d_ws;
    size_t o = 0;
    float* h1   = ws + o; o += (size_t)Nn * 128;
    float* out1 = ws + o; o += (size_t)Nn * 128;
    float* h2   = ws + o; o += (size_t)Nn * 16;
    float* a1s  = ws + o; o += (size_t)Nn * 4;
    float* a1d  = ws + o; o += (size_t)Nn * 4;
    float* a2s  = ws + o; o += (size_t)Nn;
    float* a2d  = ws + o; o += (size_t)Nn;
    int* iws    = (int*)(ws + o);
    size_t oi = 0;
    int* rowptr = iws + oi; oi += Nn + 1;
    int* cnt    = iws + oi; oi += Nn;
    int* cnt2   = iws + oi; oi += Nn;
    int* part   = iws + oi; oi += 128;
    int* srcs   = iws + oi; oi += ET;

    const int nbScan = (Nn + 1023) / 1024;

    // CSR build
    init_k<<<dim3((Nn + 255) / 256), dim3(256), 0, stream>>>(cnt, cnt2, Nn);
    hist_k<<<dim3((ET + 255) / 256), dim3(256), 0, stream>>>(ei, E, ET, cnt);
    scan_blk_k<<<dim3(nbScan), dim3(1024), 0, stream>>>(cnt, rowptr, part, Nn);
    scan_part_k<<<dim3(1), dim3(128), 0, stream>>>(part, nbScan);
    scan_add_k<<<dim3(nbScan), dim3(1024), 0, stream>>>(rowptr, part, Nn, ET);
    scatter_k<<<dim3((ET + 255) / 256), dim3(256), 0, stream>>>(ei, E, ET, rowptr, cnt2, srcs);
    // layer 1
    gemm1_k<<<dim3(Nn / 16), dim3(128), 0, stream>>>(x, W1, h1);
    acoef1_k<<<dim3((Nn * 4 + 255) / 256), dim3(256), 0, stream>>>(h1, att_s1, att_d1, a1s, a1d, Nn);
    agg1_k<<<dim3((Nn * 64 + 255) / 256), dim3(256), 0, stream>>>(rowptr, srcs, a1s, a1d, h1, b1, out1, Nn);
    // layer 2
    gemm2_k<<<dim3(Nn / 16), dim3(256), 0, stream>>>(out1, W2, att_s2, att_d2, h2, a2s, a2d);
    agg2_k<<<dim3((Nn * 64 + 255) / 256), dim3(256), 0, stream>>>(rowptr, srcs, a2s, a2d, h2, b2, dout, Nn);
}

// Round 3
// 488.284 us; speedup vs baseline: 2.8930x; 1.3021x over previous
//
#include <hip/hip_runtime.h>
#include <hip/hip_fp16.h>
#include <cfloat>
#include <cmath>

#define LEAKY 0.2f

// ---------------- init: zero CSR counters ----------------
__global__ void init_k(int* __restrict__ cnt, int* __restrict__ cnt2, int Nn) {
    int i = blockIdx.x * 256 + threadIdx.x;
    if (i < Nn) { cnt[i] = 0; cnt2[i] = 0; }
}

__device__ __forceinline__ void edge_sd(const int* __restrict__ ei, int e, int E, int& s, int& d) {
    if (e < E) { s = ei[e]; d = ei[E + e]; }
    else       { s = e - E; d = e - E; }   // self loops appended
}

// ---------------- CSR build ----------------
__global__ void hist_k(const int* __restrict__ ei, int E, int ET, int* __restrict__ cnt) {
    int e = blockIdx.x * 256 + threadIdx.x;
    if (e >= ET) return;
    int s, d; edge_sd(ei, e, E, s, d);
    atomicAdd(&cnt[d], 1);
}

__global__ __launch_bounds__(1024) void scan_blk_k(const int* __restrict__ cnt,
                                                   int* __restrict__ rowptr,
                                                   int* __restrict__ part, int Nn) {
    __shared__ int sm[1024];
    int t = threadIdx.x, i = blockIdx.x * 1024 + t;
    int v = (i < Nn) ? cnt[i] : 0;
    sm[t] = v; __syncthreads();
    for (int off = 1; off < 1024; off <<= 1) {
        int add = (t >= off) ? sm[t - off] : 0;
        __syncthreads();
        sm[t] += add;
        __syncthreads();
    }
    if (i < Nn) rowptr[i] = sm[t] - v;
    if (t == 1023) part[blockIdx.x] = sm[1023];
}

__global__ __launch_bounds__(128) void scan_part_k(int* __restrict__ part, int nb) {
    __shared__ int sm[128];
    int t = threadIdx.x;
    int v = (t < nb) ? part[t] : 0;
    sm[t] = v; __syncthreads();
    for (int off = 1; off < 128; off <<= 1) {
        int add = (t >= off) ? sm[t - off] : 0;
        __syncthreads();
        sm[t] += add;
        __syncthreads();
    }
    if (t < nb) part[t] = sm[t] - v;
}

__global__ __launch_bounds__(1024) void scan_add_k(int* __restrict__ rowptr,
                                                   const int* __restrict__ part,
                                                   int Nn, int ET) {
    int i = blockIdx.x * 1024 + threadIdx.x;
    if (i < Nn) rowptr[i] += part[blockIdx.x];
    if (i == 0) rowptr[Nn] = ET;
}

__global__ void scatter_k(const int* __restrict__ ei, int E, int ET,
                          const int* __restrict__ rowptr, int* __restrict__ cnt2,
                          int* __restrict__ srcs) {
    int e = blockIdx.x * 256 + threadIdx.x;
    if (e >= ET) return;
    int s, d; edge_sd(ei, e, E, s, d);
    int pos = rowptr[d] + atomicAdd(&cnt2[d], 1);
    srcs[pos] = s;
}

// ---------------- layer1 GEMM: h1[N,128] = x[N,256] @ W1[256,128], fp16 out ----------------
__global__ __launch_bounds__(128) void gemm1_k(const float* __restrict__ x,
                                               const float* __restrict__ W,
                                               __half* __restrict__ h1) {
    __shared__ float xs[16][256];
    const int j = threadIdx.x;
    const int rowBase = blockIdx.x * 16;
    for (int i4 = j; i4 < 1024; i4 += 128) {          // 1024 float4 = 16x256
        int r = i4 >> 6, c4 = i4 & 63;
        *(float4*)&xs[r][c4 * 4] = *(const float4*)&x[(size_t)(rowBase + r) * 256 + c4 * 4];
    }
    __syncthreads();
    float acc[16];
#pragma unroll
    for (int r = 0; r < 16; ++r) acc[r] = 0.0f;
    for (int k0 = 0; k0 < 256; k0 += 4) {
        float w0 = W[(k0 + 0) * 128 + j];
        float w1 = W[(k0 + 1) * 128 + j];
        float w2 = W[(k0 + 2) * 128 + j];
        float w3 = W[(k0 + 3) * 128 + j];
#pragma unroll
        for (int r = 0; r < 16; ++r) {
            float4 xv = *(const float4*)&xs[r][k0];   // ds_read_b128 broadcast
            acc[r] = fmaf(xv.x, w0, acc[r]);
            acc[r] = fmaf(xv.y, w1, acc[r]);
            acc[r] = fmaf(xv.z, w2, acc[r]);
            acc[r] = fmaf(xv.w, w3, acc[r]);
        }
    }
#pragma unroll
    for (int r = 0; r < 16; ++r)
        h1[(size_t)(rowBase + r) * 128 + j] = __float2half(acc[r]);
}

// ---------------- layer1 attention coefficients [N,4] (reads fp16 h1) ----------------
__global__ void acoef1_k(const __half* __restrict__ h1, const float* __restrict__ att_s,
                         const float* __restrict__ att_d, float* __restrict__ a1s,
                         float* __restrict__ a1d, int Nn) {
    int g = blockIdx.x * 256 + threadIdx.x;
    if (g >= Nn * 4) return;
    int node = g >> 2, head = g & 3;
    const __half2* hp = (const __half2*)(h1 + (size_t)node * 128 + head * 32);
    const float* as = att_s + head * 32;
    const float* ad = att_d + head * 32;
    float s = 0.0f, d = 0.0f;
#pragma unroll
    for (int c = 0; c < 16; ++c) {
        float2 v = __half22float2(hp[c]);
        s += v.x * as[2 * c] + v.y * as[2 * c + 1];
        d += v.x * ad[2 * c] + v.y * ad[2 * c + 1];
    }
    a1s[g] = s; a1d[g] = d;
}

// ---------------- layer1 fused segment softmax (no-max) + aggregate + bias + ELU ----------------
// one 64-lane wave per destination node; alphas parked in LDS
__global__ __launch_bounds__(256) void agg1_k(const int* __restrict__ rowptr,
                                              const int* __restrict__ srcs,
                                              const float* __restrict__ a1s,
                                              const float* __restrict__ a1d,
                                              const __half* __restrict__ h1,
                                              const float* __restrict__ b1,
                                              __half* __restrict__ out1, int Nn) {
    __shared__ int   s_s[4][64];
    __shared__ float s_al[4][64][4];
    const int wv = threadIdx.x >> 6;
    const int lane = threadIdx.x & 63;
    const int n = blockIdx.x * 4 + wv;
    if (n >= Nn) return;
    const int beg = rowptr[n], end = rowptr[n + 1];
    const int cnt = end - beg;
    const float4 ad4 = ((const float4*)a1d)[n];      // wave-uniform

    // window 0: each lane owns one edge, computes all 4 heads
    int e = beg + lane;
    bool val = e < end;
    int sv = val ? srcs[e] : 0;
    float4 a = ((const float4*)a1s)[sv];
    float v0 = a.x + ad4.x, v1 = a.y + ad4.y, v2 = a.z + ad4.z, v3 = a.w + ad4.w;
    v0 = fmaxf(v0, LEAKY * v0); v1 = fmaxf(v1, LEAKY * v1);
    v2 = fmaxf(v2, LEAKY * v2); v3 = fmaxf(v3, LEAKY * v3);
    float al0 = val ? __expf(v0) : 0.0f, al1 = val ? __expf(v1) : 0.0f;
    float al2 = val ? __expf(v2) : 0.0f, al3 = val ? __expf(v3) : 0.0f;
    float t0 = al0, t1 = al1, t2 = al2, t3 = al3;
    for (int base = beg + 64; base < end; base += 64) {   // rare (deg>64)
        int ee = base + lane; bool vv = ee < end;
        int ss = vv ? srcs[ee] : 0;
        float4 aa = ((const float4*)a1s)[ss];
        float w0 = aa.x + ad4.x, w1 = aa.y + ad4.y, w2 = aa.z + ad4.z, w3 = aa.w + ad4.w;
        w0 = fmaxf(w0, LEAKY * w0); w1 = fmaxf(w1, LEAKY * w1);
        w2 = fmaxf(w2, LEAKY * w2); w3 = fmaxf(w3, LEAKY * w3);
        if (vv) { t0 += __expf(w0); t1 += __expf(w1); t2 += __expf(w2); t3 += __expf(w3); }
    }
#pragma unroll
    for (int off = 1; off < 64; off <<= 1) {
        t0 += __shfl_xor(t0, off); t1 += __shfl_xor(t1, off);
        t2 += __shfl_xor(t2, off); t3 += __shfl_xor(t3, off);
    }
    const float i0 = 1.0f / (t0 + 1e-16f), i1 = 1.0f / (t1 + 1e-16f);
    const float i2 = 1.0f / (t2 + 1e-16f), i3 = 1.0f / (t3 + 1e-16f);

    const int hc = lane >> 4;                         // head for owned cols
    float2 acc = make_float2(0.0f, 0.0f);

    // window 0 aggregate (alphas already in regs)
    s_s[wv][lane] = sv;
    s_al[wv][lane][0] = al0 * i0; s_al[wv][lane][1] = al1 * i1;
    s_al[wv][lane][2] = al2 * i2; s_al[wv][lane][3] = al3 * i3;
    int wcnt = cnt < 64 ? cnt : 64;
    for (int ko = 0; ko < wcnt; ++ko) {
        int s = s_s[wv][ko];
        float al = s_al[wv][ko][hc];
        float2 hv = __half22float2(*(const __half2*)&h1[(size_t)s * 128 + 2 * lane]);
        acc.x = fmaf(al, hv.x, acc.x);
        acc.y = fmaf(al, hv.y, acc.y);
    }
    for (int base = beg + 64; base < end; base += 64) {   // rare
        int ee = base + lane; bool vv = ee < end;
        int ss = vv ? srcs[ee] : 0;
        float4 aa = ((const float4*)a1s)[ss];
        float w0 = aa.x + ad4.x, w1 = aa.y + ad4.y, w2 = aa.z + ad4.z, w3 = aa.w + ad4.w;
        w0 = fmaxf(w0, LEAKY * w0); w1 = fmaxf(w1, LEAKY * w1);
        w2 = fmaxf(w2, LEAKY * w2); w3 = fmaxf(w3, LEAKY * w3);
        s_s[wv][lane] = ss;
        s_al[wv][lane][0] = vv ? __expf(w0) * i0 : 0.0f;
        s_al[wv][lane][1] = vv ? __expf(w1) * i1 : 0.0f;
        s_al[wv][lane][2] = vv ? __expf(w2) * i2 : 0.0f;
        s_al[wv][lane][3] = vv ? __expf(w3) * i3 : 0.0f;
        int wc = end - base; if (wc > 64) wc = 64;
        for (int ko = 0; ko < wc; ++ko) {
            int s = s_s[wv][ko];
            float al = s_al[wv][ko][hc];
            float2 hv = __half22float2(*(const __half2*)&h1[(size_t)s * 128 + 2 * lane]);
            acc.x = fmaf(al, hv.x, acc.x);
            acc.y = fmaf(al, hv.y, acc.y);
        }
    }
    float2 bb = *(const float2*)&b1[2 * lane];
    float ox = acc.x + bb.x, oy = acc.y + bb.y;
    ox = ox > 0.0f ? ox : expm1f(ox);                 // ELU fused
    oy = oy > 0.0f ? oy : expm1f(oy);
    *(__half2*)&out1[(size_t)n * 128 + 2 * lane] = __floats2half2_rn(ox, oy);
}

// ---------------- layer2 GEMM (fp16 in) + attention coefficients ----------------
__global__ __launch_bounds__(256) void gemm2_k(const __half* __restrict__ hin,
                                               const float* __restrict__ W2,
                                               const float* __restrict__ att_s2,
                                               const float* __restrict__ att_d2,
                                               __half* __restrict__ h2,
                                               float* __restrict__ a2s, float* __restrict__ a2d) {
    __shared__ float hs[16][132];                     // 132: float4-aligned rows
    __shared__ float w2s[128 * 16];
    const int t = threadIdx.x;
    const int nodeBase = blockIdx.x * 16;
    for (int i2 = t; i2 < 1024; i2 += 256) {          // 1024 half2 = 16x128
        float2 v = __half22float2(*(const __half2*)&hin[(size_t)nodeBase * 128 + i2 * 2]);
        int r = i2 >> 6, c = (i2 & 63) * 2;
        hs[r][c] = v.x; hs[r][c + 1] = v.y;
    }
    for (int i4 = t; i4 < 512; i4 += 256)
        *(float4*)&w2s[i4 * 4] = *(const float4*)&W2[i4 * 4];
    __syncthreads();
    const int ln = t >> 4, j = t & 15;
    float acc = 0.0f;
    for (int k0 = 0; k0 < 128; k0 += 4) {
        float4 hv = *(const float4*)&hs[ln][k0];
        acc = fmaf(hv.x, w2s[(k0 + 0) * 16 + j], acc);
        acc = fmaf(hv.y, w2s[(k0 + 1) * 16 + j], acc);
        acc = fmaf(hv.z, w2s[(k0 + 2) * 16 + j], acc);
        acc = fmaf(hv.w, w2s[(k0 + 3) * 16 + j], acc);
    }
    const int node = nodeBase + ln;
    h2[(size_t)node * 16 + j] = __float2half(acc);
    float vs = acc * att_s2[j];
    float vd = acc * att_d2[j];
#pragma unroll
    for (int off = 8; off; off >>= 1) {
        vs += __shfl_xor(vs, off);
        vd += __shfl_xor(vd, off);
    }
    if (j == 0) { a2s[node] = vs; a2d[node] = vd; }
}

// ---------------- layer2 fused softmax (no-max) + aggregate + bias ----------------
__global__ __launch_bounds__(256) void agg2_k(const int* __restrict__ rowptr,
                                              const int* __restrict__ srcs,
                                              const float* __restrict__ a2s,
                                              const float* __restrict__ a2d,
                                              const __half* __restrict__ h2,
                                              const float* __restrict__ b2,
                                              float* __restrict__ dout, int Nn) {
    __shared__ int   s_s[4][64];
    __shared__ float s_al[4][64];
    const int wv = threadIdx.x >> 6;
    const int lane = threadIdx.x & 63;
    const int n = blockIdx.x * 4 + wv;
    if (n >= Nn) return;
    const int beg = rowptr[n], end = rowptr[n + 1];
    const int cnt = end - beg;
    const float adn = a2d[n];

    int e = beg + lane;
    bool val = e < end;
    int sv = val ? srcs[e] : 0;
    float av = a2s[sv] + adn;
    av = fmaxf(av, LEAKY * av);
    float al = val ? __expf(av) : 0.0f;
    float ss = al;
    for (int base = beg + 64; base < end; base += 64) {   // rare
        int ee = base + lane; bool vv = ee < end;
        float aw = a2s[vv ? srcs[ee] : 0] + adn;
        aw = fmaxf(aw, LEAKY * aw);
        if (vv) ss += __expf(aw);
    }
#pragma unroll
    for (int off = 1; off < 64; off <<= 1) ss += __shfl_xor(ss, off);
    const float sinv = 1.0f / (ss + 1e-16f);

    const int eg = lane >> 4, j = lane & 15;
    float acc = 0.0f;
    s_s[wv][lane] = sv;
    s_al[wv][lane] = al * sinv;
    int wcnt = cnt < 64 ? cnt : 64;
    for (int ko = eg; ko < wcnt; ko += 4) {
        int s = s_s[wv][ko];
        float a2 = s_al[wv][ko];
        acc = fmaf(a2, __half2float(h2[(size_t)s * 16 + j]), acc);
    }
    for (int base = beg + 64; base < end; base += 64) {   // rare
        int ee = base + lane; bool vv = ee < end;
        int sn = vv ? srcs[ee] : 0;
        float aw = a2s[sn] + adn;
        aw = fmaxf(aw, LEAKY * aw);
        s_s[wv][lane] = sn;
        s_al[wv][lane] = vv ? __expf(aw) * sinv : 0.0f;
        int wc = end - base; if (wc > 64) wc = 64;
        for (int ko = eg; ko < wc; ko += 4) {
            int s = s_s[wv][ko];
            float a2 = s_al[wv][ko];
            acc = fmaf(a2, __half2float(h2[(size_t)s * 16 + j]), acc);
        }
    }
    acc += __shfl_xor(acc, 16);
    acc += __shfl_xor(acc, 32);
    if (lane < 16) dout[(size_t)n * 16 + j] = acc + b2[j];
}

extern "C" void kernel_launch(void* const* d_in, const int* in_sizes, int n_in,
                              void* d_out, int out_size, void* d_ws, size_t ws_size,
                              hipStream_t stream) {
    const float* x      = (const float*)d_in[0];
    const int*   ei     = (const int*)d_in[1];
    const float* W1     = (const float*)d_in[2];
    const float* att_s1 = (const float*)d_in[3];
    const float* att_d1 = (const float*)d_in[4];
    const float* b1     = (const float*)d_in[5];
    const float* W2     = (const float*)d_in[6];
    const float* att_s2 = (const float*)d_in[7];
    const float* att_d2 = (const float*)d_in[8];
    const float* b2     = (const float*)d_in[9];
    float* dout = (float*)d_out;

    const int Nn = in_sizes[0] / 256;     // 100000
    const int E  = in_sizes[1] / 2;       // 1600000
    const int ET = E + Nn;

    char* p = (char*)d_ws;
    auto alloc = [&](size_t bytes) { char* r = p; p += (bytes + 255) & ~(size_t)255; return r; };
    __half* h1   = (__half*)alloc((size_t)Nn * 128 * 2);
    __half* out1 = (__half*)alloc((size_t)Nn * 128 * 2);
    __half* h2   = (__half*)alloc((size_t)Nn * 16 * 2);
    float* a1s   = (float*)alloc((size_t)Nn * 4 * 4);
    float* a1d   = (float*)alloc((size_t)Nn * 4 * 4);
    float* a2s   = (float*)alloc((size_t)Nn * 4);
    float* a2d   = (float*)alloc((size_t)Nn * 4);
    int* rowptr  = (int*)alloc((size_t)(Nn + 1) * 4);
    int* cnt     = (int*)alloc((size_t)Nn * 4);
    int* cnt2    = (int*)alloc((size_t)Nn * 4);
    int* part    = (int*)alloc(128 * 4);
    int* srcs    = (int*)alloc((size_t)ET * 4);

    const int nbScan = (Nn + 1023) / 1024;

    // CSR build
    init_k<<<dim3((Nn + 255) / 256), dim3(256), 0, stream>>>(cnt, cnt2, Nn);
    hist_k<<<dim3((ET + 255) / 256), dim3(256), 0, stream>>>(ei, E, ET, cnt);
    scan_blk_k<<<dim3(nbScan), dim3(1024), 0, stream>>>(cnt, rowptr, part, Nn);
    scan_part_k<<<dim3(1), dim3(128), 0, stream>>>(part, nbScan);
    scan_add_k<<<dim3(nbScan), dim3(1024), 0, stream>>>(rowptr, part, Nn, ET);
    scatter_k<<<dim3((ET + 255) / 256), dim3(256), 0, stream>>>(ei, E, ET, rowptr, cnt2, srcs);
    // layer 1
    gemm1_k<<<dim3(Nn / 16), dim3(128), 0, stream>>>(x, W1, h1);
    acoef1_k<<<dim3((Nn * 4 + 255) / 256), dim3(256), 0, stream>>>(h1, att_s1, att_d1, a1s, a1d, Nn);
    agg1_k<<<dim3((Nn + 3) / 4), dim3(256), 0, stream>>>(rowptr, srcs, a1s, a1d, h1, b1, out1, Nn);
    // layer 2
    gemm2_k<<<dim3(Nn / 16), dim3(256), 0, stream>>>(out1, W2, att_s2, att_d2, h2, a2s, a2d);
    agg2_k<<<dim3((Nn + 3) / 4), dim3(256), 0, stream>>>(rowptr, srcs, a2s, a2d, h2, b2, dout, Nn);
}

// Round 4
// 375.144 us; speedup vs baseline: 3.7655x; 1.3016x over previous
//
#include <hip/hip_runtime.h>
#include <hip/hip_fp16.h>
#include <cfloat>
#include <cmath>

#define LEAKY 0.2f

typedef _Float16 half8 __attribute__((ext_vector_type(8)));
typedef float f32x4 __attribute__((ext_vector_type(4)));

// ---------------- init: zero CSR counters ----------------
__global__ void init_k(int* __restrict__ cnt, int* __restrict__ cnt2, int Nn) {
    int i = blockIdx.x * 256 + threadIdx.x;
    if (i < Nn) { cnt[i] = 0; cnt2[i] = 0; }
}

__device__ __forceinline__ void edge_sd(const int* __restrict__ ei, int e, int E, int& s, int& d) {
    if (e < E) { s = ei[e]; d = ei[E + e]; }
    else       { s = e - E; d = e - E; }   // self loops appended
}

// ---------------- CSR build ----------------
__global__ void hist_k(const int* __restrict__ ei, int E, int ET, int* __restrict__ cnt) {
    int e = blockIdx.x * 256 + threadIdx.x;
    if (e >= ET) return;
    int s, d; edge_sd(ei, e, E, s, d);
    atomicAdd(&cnt[d], 1);
}

__global__ __launch_bounds__(1024) void scan_blk_k(const int* __restrict__ cnt,
                                                   int* __restrict__ rowptr,
                                                   int* __restrict__ part, int Nn) {
    __shared__ int sm[1024];
    int t = threadIdx.x, i = blockIdx.x * 1024 + t;
    int v = (i < Nn) ? cnt[i] : 0;
    sm[t] = v; __syncthreads();
    for (int off = 1; off < 1024; off <<= 1) {
        int add = (t >= off) ? sm[t - off] : 0;
        __syncthreads();
        sm[t] += add;
        __syncthreads();
    }
    if (i < Nn) rowptr[i] = sm[t] - v;
    if (t == 1023) part[blockIdx.x] = sm[1023];
}

__global__ __launch_bounds__(128) void scan_part_k(int* __restrict__ part, int nb) {
    __shared__ int sm[128];
    int t = threadIdx.x;
    int v = (t < nb) ? part[t] : 0;
    sm[t] = v; __syncthreads();
    for (int off = 1; off < 128; off <<= 1) {
        int add = (t >= off) ? sm[t - off] : 0;
        __syncthreads();
        sm[t] += add;
        __syncthreads();
    }
    if (t < nb) part[t] = sm[t] - v;
}

__global__ __launch_bounds__(1024) void scan_add_k(int* __restrict__ rowptr,
                                                   const int* __restrict__ part,
                                                   int Nn, int ET) {
    int i = blockIdx.x * 1024 + threadIdx.x;
    if (i < Nn) rowptr[i] += part[blockIdx.x];
    if (i == 0) rowptr[Nn] = ET;
}

__global__ void scatter_k(const int* __restrict__ ei, int E, int ET,
                          const int* __restrict__ rowptr, int* __restrict__ cnt2,
                          int* __restrict__ srcs) {
    int e = blockIdx.x * 256 + threadIdx.x;
    if (e >= ET) return;
    int s, d; edge_sd(ei, e, E, s, d);
    int pos = rowptr[d] + atomicAdd(&cnt2[d], 1);
    srcs[pos] = s;
}

// ---------------- W1 pack into MFMA B-fragment order, fp16 ----------------
// Wpk[((t*8+s)*64+l)*8+j] = W1[s*32+(l>>4)*8+j][t*16+(l&15)]
__global__ void wpack1_k(const float* __restrict__ W1, _Float16* __restrict__ Wpk) {
    int g = blockIdx.x * 256 + threadIdx.x;
    if (g >= 4096) return;
    int t = g >> 9, s = (g >> 6) & 7, l = g & 63;
    int krow = s * 32 + ((l >> 4) << 3);
    int col = t * 16 + (l & 15);
    half8 v;
#pragma unroll
    for (int j = 0; j < 8; ++j) v[j] = (_Float16)W1[(size_t)(krow + j) * 128 + col];
    *(half8*)&Wpk[(size_t)g * 8] = v;
}

// ---------------- layer1 GEMM via MFMA: h1[N,128] = fp16(x) @ fp16(W1) ----------------
// persistent blocks; 8 waves: mstr=w>>2 (16-row stripe), npair=w&3 (2 n-tiles)
__global__ __launch_bounds__(512) void gemm1_k(const float* __restrict__ x,
                                               const _Float16* __restrict__ Wpk,
                                               _Float16* __restrict__ h1, int Mt) {
    __shared__ __align__(16) _Float16 xs[32 * 256];   // 16 KB, XOR-swizzled
    const int t = threadIdx.x;
    const int l = t & 63;
    const int w = t >> 6;
    const int mstr = w >> 2;
    const int npair = w & 3;

    // B fragments reg-resident for whole kernel (2 n-tiles x 8 k-steps)
    half8 bf0[8], bf1[8];
#pragma unroll
    for (int s = 0; s < 8; ++s) {
        bf0[s] = *(const half8*)&Wpk[(size_t)(((npair * 2 + 0) * 8 + s) * 64 + l) * 8];
        bf1[s] = *(const half8*)&Wpk[(size_t)(((npair * 2 + 1) * 8 + s) * 64 + l) * 8];
    }

    const int r = t >> 4;                 // staging row 0..31
    const int kc = t & 15;                // k-chunk
    const int swz = (r & 7) << 4;
    const int arow = mstr * 16 + (l & 15);
    const int aswz = (arow & 7) << 4;
    const int abase = arow * 256;

    for (int mt = blockIdx.x; mt < Mt; mt += gridDim.x) {
        const int mBase = mt * 32;
        // stage: 32x256 f32 -> fp16 LDS (swizzled)
        const float4* xrow = (const float4*)(x + (size_t)(mBase + r) * 256);
#pragma unroll
        for (int i = 0; i < 4; ++i) {
            float4 v = xrow[kc + i * 16];
            union { _Float16 h[4]; uint2 u; } cv;
            cv.h[0] = (_Float16)v.x; cv.h[1] = (_Float16)v.y;
            cv.h[2] = (_Float16)v.z; cv.h[3] = (_Float16)v.w;
            int kb = kc * 8 + i * 128;
            *(uint2*)&xs[r * 256 + ((kb ^ swz) >> 1)] = cv.u;
        }
        __syncthreads();
        f32x4 acc0 = {0.f, 0.f, 0.f, 0.f}, acc1 = {0.f, 0.f, 0.f, 0.f};
#pragma unroll
        for (int s = 0; s < 8; ++s) {
            int kb = s * 64 + ((l >> 4) << 4);
            half8 a = *(const half8*)&xs[abase + ((kb ^ aswz) >> 1)];
            acc0 = __builtin_amdgcn_mfma_f32_16x16x32_f16(a, bf0[s], acc0, 0, 0, 0);
            acc1 = __builtin_amdgcn_mfma_f32_16x16x32_f16(a, bf1[s], acc1, 0, 0, 0);
        }
        // D: col=lane&15, row=(lane>>4)*4+rr  [m89]
        const int drow = mBase + mstr * 16 + ((l >> 4) << 2);
        const int dcol = npair * 32 + (l & 15);
#pragma unroll
        for (int rr = 0; rr < 4; ++rr) {
            h1[(size_t)(drow + rr) * 128 + dcol]      = (_Float16)acc0[rr];
            h1[(size_t)(drow + rr) * 128 + dcol + 16] = (_Float16)acc1[rr];
        }
        __syncthreads();
    }
}

// ---------------- layer1 attention coefficients [N,4] ----------------
__global__ void acoef1_k(const __half* __restrict__ h1, const float* __restrict__ att_s,
                         const float* __restrict__ att_d, float* __restrict__ a1s,
                         float* __restrict__ a1d, int Nn) {
    int g = blockIdx.x * 256 + threadIdx.x;
    if (g >= Nn * 4) return;
    int node = g >> 2, head = g & 3;
    const __half2* hp = (const __half2*)(h1 + (size_t)node * 128 + head * 32);
    const float* as = att_s + head * 32;
    const float* ad = att_d + head * 32;
    float s = 0.0f, d = 0.0f;
#pragma unroll
    for (int c = 0; c < 16; ++c) {
        float2 v = __half22float2(hp[c]);
        s += v.x * as[2 * c] + v.y * as[2 * c + 1];
        d += v.x * ad[2 * c] + v.y * ad[2 * c + 1];
    }
    a1s[g] = s; a1d[g] = d;
}

// ---------------- layer1 fused: softmax(no-max) + aggregate + bias + ELU
//                  + gemm2 (row @ W2) + acoef2 --------------------------------
// one 64-lane wave per destination node
__global__ __launch_bounds__(256) void agg1_k(const int* __restrict__ rowptr,
                                              const int* __restrict__ srcs,
                                              const float* __restrict__ a1s,
                                              const float* __restrict__ a1d,
                                              const __half* __restrict__ h1,
                                              const float* __restrict__ b1,
                                              const float* __restrict__ W2,
                                              const float* __restrict__ att_s2,
                                              const float* __restrict__ att_d2,
                                              __half* __restrict__ h2,
                                              float* __restrict__ a2s,
                                              float* __restrict__ a2d, int Nn) {
    __shared__ int   s_s[4][64];
    __shared__ float s_al[4][64][4];
    __shared__ float rowb[4][128];
    __shared__ float w2s[128 * 16];
    const int wv = threadIdx.x >> 6;
    const int lane = threadIdx.x & 63;
    const int n = blockIdx.x * 4 + wv;

    // stage W2 (8 KB)
    for (int i4 = threadIdx.x; i4 < 512; i4 += 256)
        *(float4*)&w2s[i4 * 4] = *(const float4*)&W2[i4 * 4];

    if (n < Nn) {
        const int beg = rowptr[n], end = rowptr[n + 1];
        const int cnt = end - beg;
        const float4 ad4 = ((const float4*)a1d)[n];

        int e = beg + lane;
        bool val = e < end;
        int sv = val ? srcs[e] : 0;
        float4 a = ((const float4*)a1s)[sv];
        float v0 = a.x + ad4.x, v1 = a.y + ad4.y, v2 = a.z + ad4.z, v3 = a.w + ad4.w;
        v0 = fmaxf(v0, LEAKY * v0); v1 = fmaxf(v1, LEAKY * v1);
        v2 = fmaxf(v2, LEAKY * v2); v3 = fmaxf(v3, LEAKY * v3);
        float al0 = val ? __expf(v0) : 0.0f, al1 = val ? __expf(v1) : 0.0f;
        float al2 = val ? __expf(v2) : 0.0f, al3 = val ? __expf(v3) : 0.0f;
        float t0 = al0, t1 = al1, t2 = al2, t3 = al3;
        for (int base = beg + 64; base < end; base += 64) {   // rare (deg>64)
            int ee = base + lane; bool vv = ee < end;
            int ss = vv ? srcs[ee] : 0;
            float4 aa = ((const float4*)a1s)[ss];
            float w0 = aa.x + ad4.x, w1 = aa.y + ad4.y, w2v = aa.z + ad4.z, w3 = aa.w + ad4.w;
            w0 = fmaxf(w0, LEAKY * w0); w1 = fmaxf(w1, LEAKY * w1);
            w2v = fmaxf(w2v, LEAKY * w2v); w3 = fmaxf(w3, LEAKY * w3);
            if (vv) { t0 += __expf(w0); t1 += __expf(w1); t2 += __expf(w2v); t3 += __expf(w3); }
        }
#pragma unroll
        for (int off = 1; off < 64; off <<= 1) {
            t0 += __shfl_xor(t0, off); t1 += __shfl_xor(t1, off);
            t2 += __shfl_xor(t2, off); t3 += __shfl_xor(t3, off);
        }
        const float i0 = 1.0f / (t0 + 1e-16f), i1 = 1.0f / (t1 + 1e-16f);
        const float i2 = 1.0f / (t2 + 1e-16f), i3 = 1.0f / (t3 + 1e-16f);

        const int hc = lane >> 4;
        float2 acc = make_float2(0.0f, 0.0f);

        s_s[wv][lane] = sv;
        s_al[wv][lane][0] = al0 * i0; s_al[wv][lane][1] = al1 * i1;
        s_al[wv][lane][2] = al2 * i2; s_al[wv][lane][3] = al3 * i3;
        int wcnt = cnt < 64 ? cnt : 64;
        for (int ko = 0; ko < wcnt; ++ko) {
            int s = s_s[wv][ko];
            float al = s_al[wv][ko][hc];
            float2 hv = __half22float2(*(const __half2*)&h1[(size_t)s * 128 + 2 * lane]);
            acc.x = fmaf(al, hv.x, acc.x);
            acc.y = fmaf(al, hv.y, acc.y);
        }
        for (int base = beg + 64; base < end; base += 64) {   // rare
            int ee = base + lane; bool vv = ee < end;
            int ss = vv ? srcs[ee] : 0;
            float4 aa = ((const float4*)a1s)[ss];
            float w0 = aa.x + ad4.x, w1 = aa.y + ad4.y, w2v = aa.z + ad4.z, w3 = aa.w + ad4.w;
            w0 = fmaxf(w0, LEAKY * w0); w1 = fmaxf(w1, LEAKY * w1);
            w2v = fmaxf(w2v, LEAKY * w2v); w3 = fmaxf(w3, LEAKY * w3);
            s_s[wv][lane] = ss;
            s_al[wv][lane][0] = vv ? __expf(w0) * i0 : 0.0f;
            s_al[wv][lane][1] = vv ? __expf(w1) * i1 : 0.0f;
            s_al[wv][lane][2] = vv ? __expf(w2v) * i2 : 0.0f;
            s_al[wv][lane][3] = vv ? __expf(w3) * i3 : 0.0f;
            int wc = end - base; if (wc > 64) wc = 64;
            for (int ko = 0; ko < wc; ++ko) {
                int s = s_s[wv][ko];
                float al = s_al[wv][ko][hc];
                float2 hv = __half22float2(*(const __half2*)&h1[(size_t)s * 128 + 2 * lane]);
                acc.x = fmaf(al, hv.x, acc.x);
                acc.y = fmaf(al, hv.y, acc.y);
            }
        }
        float2 bb = *(const float2*)&b1[2 * lane];
        float ox = acc.x + bb.x, oy = acc.y + bb.y;
        ox = ox > 0.0f ? ox : expm1f(ox);                 // ELU
        oy = oy > 0.0f ? oy : expm1f(oy);
        rowb[wv][2 * lane] = ox;
        rowb[wv][2 * lane + 1] = oy;
    }
    __syncthreads();   // covers w2s staging + rowb cross-lane
    if (n >= Nn) return;

    // fused layer2 GEMM row: h2[n][j] = rowb . W2[:,j] ; + acoef2
    const int q = lane >> 4, j = lane & 15;
    const float* rb = rowb[wv];
    float part = 0.0f;
#pragma unroll
    for (int kk = 0; kk < 32; ++kk) {
        int k = q * 32 + kk;
        part = fmaf(rb[k], w2s[k * 16 + j], part);
    }
    part += __shfl_xor(part, 16);
    part += __shfl_xor(part, 32);                 // all lanes: h2[n][j]
    float vs = part * att_s2[j];
    float vd = part * att_d2[j];
#pragma unroll
    for (int off = 1; off < 16; off <<= 1) {
        vs += __shfl_xor(vs, off);
        vd += __shfl_xor(vd, off);
    }
    if (lane < 16) h2[(size_t)n * 16 + j] = __float2half(part);
    if (lane == 0) { a2s[n] = vs; a2d[n] = vd; }
}

// ---------------- layer2 fused softmax (no-max) + aggregate + bias ----------------
__global__ __launch_bounds__(256) void agg2_k(const int* __restrict__ rowptr,
                                              const int* __restrict__ srcs,
                                              const float* __restrict__ a2s,
                                              const float* __restrict__ a2d,
                                              const __half* __restrict__ h2,
                                              const float* __restrict__ b2,
                                              float* __restrict__ dout, int Nn) {
    __shared__ int   s_s[4][64];
    __shared__ float s_al[4][64];
    const int wv = threadIdx.x >> 6;
    const int lane = threadIdx.x & 63;
    const int n = blockIdx.x * 4 + wv;
    if (n >= Nn) return;
    const int beg = rowptr[n], end = rowptr[n + 1];
    const int cnt = end - beg;
    const float adn = a2d[n];

    int e = beg + lane;
    bool val = e < end;
    int sv = val ? srcs[e] : 0;
    float av = a2s[sv] + adn;
    av = fmaxf(av, LEAKY * av);
    float al = val ? __expf(av) : 0.0f;
    float ss = al;
    for (int base = beg + 64; base < end; base += 64) {
        int ee = base + lane; bool vv = ee < end;
        float aw = a2s[vv ? srcs[ee] : 0] + adn;
        aw = fmaxf(aw, LEAKY * aw);
        if (vv) ss += __expf(aw);
    }
#pragma unroll
    for (int off = 1; off < 64; off <<= 1) ss += __shfl_xor(ss, off);
    const float sinv = 1.0f / (ss + 1e-16f);

    const int eg = lane >> 4, j = lane & 15;
    float acc = 0.0f;
    s_s[wv][lane] = sv;
    s_al[wv][lane] = al * sinv;
    int wcnt = cnt < 64 ? cnt : 64;
    for (int ko = eg; ko < wcnt; ko += 4) {
        acc = fmaf(s_al[wv][ko], __half2float(h2[(size_t)s_s[wv][ko] * 16 + j]), acc);
    }
    for (int base = beg + 64; base < end; base += 64) {
        int ee = base + lane; bool vv = ee < end;
        int sn = vv ? srcs[ee] : 0;
        float aw = a2s[sn] + adn;
        aw = fmaxf(aw, LEAKY * aw);
        s_s[wv][lane] = sn;
        s_al[wv][lane] = vv ? __expf(aw) * sinv : 0.0f;
        int wc = end - base; if (wc > 64) wc = 64;
        for (int ko = eg; ko < wc; ko += 4) {
            acc = fmaf(s_al[wv][ko], __half2float(h2[(size_t)s_s[wv][ko] * 16 + j]), acc);
        }
    }
    acc += __shfl_xor(acc, 16);
    acc += __shfl_xor(acc, 32);
    if (lane < 16) dout[(size_t)n * 16 + j] = acc + b2[j];
}

extern "C" void kernel_launch(void* const* d_in, const int* in_sizes, int n_in,
                              void* d_out, int out_size, void* d_ws, size_t ws_size,
                              hipStream_t stream) {
    const float* x      = (const float*)d_in[0];
    const int*   ei     = (const int*)d_in[1];
    const float* W1     = (const float*)d_in[2];
    const float* att_s1 = (const float*)d_in[3];
    const float* att_d1 = (const float*)d_in[4];
    const float* b1     = (const float*)d_in[5];
    const float* W2     = (const float*)d_in[6];
    const float* att_s2 = (const float*)d_in[7];
    const float* att_d2 = (const float*)d_in[8];
    const float* b2     = (const float*)d_in[9];
    float* dout = (float*)d_out;

    const int Nn = in_sizes[0] / 256;     // 100000
    const int E  = in_sizes[1] / 2;       // 1600000
    const int ET = E + Nn;

    char* p = (char*)d_ws;
    auto alloc = [&](size_t bytes) { char* r = p; p += (bytes + 255) & ~(size_t)255; return r; };
    _Float16* h1  = (_Float16*)alloc((size_t)Nn * 128 * 2);
    __half* h2    = (__half*)alloc((size_t)Nn * 16 * 2);
    _Float16* Wpk = (_Float16*)alloc(4096 * 8 * 2);
    float* a1s    = (float*)alloc((size_t)Nn * 4 * 4);
    float* a1d    = (float*)alloc((size_t)Nn * 4 * 4);
    float* a2s    = (float*)alloc((size_t)Nn * 4);
    float* a2d    = (float*)alloc((size_t)Nn * 4);
    int* rowptr   = (int*)alloc((size_t)(Nn + 1) * 4);
    int* cnt      = (int*)alloc((size_t)Nn * 4);
    int* cnt2     = (int*)alloc((size_t)Nn * 4);
    int* part     = (int*)alloc(128 * 4);
    int* srcs     = (int*)alloc((size_t)ET * 4);

    const int nbScan = (Nn + 1023) / 1024;

    // CSR build
    init_k<<<dim3((Nn + 255) / 256), dim3(256), 0, stream>>>(cnt, cnt2, Nn);
    hist_k<<<dim3((ET + 255) / 256), dim3(256), 0, stream>>>(ei, E, ET, cnt);
    scan_blk_k<<<dim3(nbScan), dim3(1024), 0, stream>>>(cnt, rowptr, part, Nn);
    scan_part_k<<<dim3(1), dim3(128), 0, stream>>>(part, nbScan);
    scan_add_k<<<dim3(nbScan), dim3(1024), 0, stream>>>(rowptr, part, Nn, ET);
    scatter_k<<<dim3((ET + 255) / 256), dim3(256), 0, stream>>>(ei, E, ET, rowptr, cnt2, srcs);
    // layer 1
    wpack1_k<<<dim3(16), dim3(256), 0, stream>>>(W1, Wpk);
    gemm1_k<<<dim3(512), dim3(512), 0, stream>>>(x, Wpk, h1, Nn / 32);
    acoef1_k<<<dim3((Nn * 4 + 255) / 256), dim3(256), 0, stream>>>((const __half*)h1, att_s1, att_d1, a1s, a1d, Nn);
    // fused agg1 + gemm2 + acoef2
    agg1_k<<<dim3((Nn + 3) / 4), dim3(256), 0, stream>>>(rowptr, srcs, a1s, a1d,
                                                         (const __half*)h1, b1,
                                                         W2, att_s2, att_d2,
                                                         h2, a2s, a2d, Nn);
    // layer 2 aggregation
    agg2_k<<<dim3((Nn + 3) / 4), dim3(256), 0, stream>>>(rowptr, srcs, a2s, a2d, h2, b2, dout, Nn);
}

// Round 5
// 368.653 us; speedup vs baseline: 3.8318x; 1.0176x over previous
//
#include <hip/hip_runtime.h>
#include <hip/hip_fp16.h>
#include <cfloat>
#include <cmath>

#define LEAKY 0.2f

typedef _Float16 half8 __attribute__((ext_vector_type(8)));
typedef float f32x4 __attribute__((ext_vector_type(4)));

// ---------------- init: zero CSR counters ----------------
__global__ void init_k(int* __restrict__ cnt, int* __restrict__ cnt2, int Nn) {
    int i = blockIdx.x * 256 + threadIdx.x;
    if (i < Nn) { cnt[i] = 0; cnt2[i] = 0; }
}

__device__ __forceinline__ void edge_sd(const int* __restrict__ ei, int e, int E, int& s, int& d) {
    if (e < E) { s = ei[e]; d = ei[E + e]; }
    else       { s = e - E; d = e - E; }   // self loops appended
}

// ---------------- CSR build ----------------
__global__ void hist_k(const int* __restrict__ ei, int E, int ET, int* __restrict__ cnt) {
    int e = blockIdx.x * 256 + threadIdx.x;
    if (e >= ET) return;
    int s, d; edge_sd(ei, e, E, s, d);
    atomicAdd(&cnt[d], 1);
}

__global__ __launch_bounds__(1024) void scan_blk_k(const int* __restrict__ cnt,
                                                   int* __restrict__ rowptr,
                                                   int* __restrict__ part, int Nn) {
    __shared__ int sm[1024];
    int t = threadIdx.x, i = blockIdx.x * 1024 + t;
    int v = (i < Nn) ? cnt[i] : 0;
    sm[t] = v; __syncthreads();
    for (int off = 1; off < 1024; off <<= 1) {
        int add = (t >= off) ? sm[t - off] : 0;
        __syncthreads();
        sm[t] += add;
        __syncthreads();
    }
    if (i < Nn) rowptr[i] = sm[t] - v;
    if (t == 1023) part[blockIdx.x] = sm[1023];
}

__global__ __launch_bounds__(128) void scan_part_k(int* __restrict__ part, int nb) {
    __shared__ int sm[128];
    int t = threadIdx.x;
    int v = (t < nb) ? part[t] : 0;
    sm[t] = v; __syncthreads();
    for (int off = 1; off < 128; off <<= 1) {
        int add = (t >= off) ? sm[t - off] : 0;
        __syncthreads();
        sm[t] += add;
        __syncthreads();
    }
    if (t < nb) part[t] = sm[t] - v;
}

__global__ __launch_bounds__(1024) void scan_add_k(int* __restrict__ rowptr,
                                                   const int* __restrict__ part,
                                                   int Nn, int ET) {
    int i = blockIdx.x * 1024 + threadIdx.x;
    if (i < Nn) rowptr[i] += part[blockIdx.x];
    if (i == 0) rowptr[Nn] = ET;
}

__global__ void scatter_k(const int* __restrict__ ei, int E, int ET,
                          const int* __restrict__ rowptr, int* __restrict__ cnt2,
                          int* __restrict__ srcs) {
    int e = blockIdx.x * 256 + threadIdx.x;
    if (e >= ET) return;
    int s, d; edge_sd(ei, e, E, s, d);
    int pos = rowptr[d] + atomicAdd(&cnt2[d], 1);
    srcs[pos] = s;
}

// ---------------- W1 pack into MFMA B-fragment order, fp16 ----------------
__global__ void wpack1_k(const float* __restrict__ W1, _Float16* __restrict__ Wpk) {
    int g = blockIdx.x * 256 + threadIdx.x;
    if (g >= 4096) return;
    int t = g >> 9, s = (g >> 6) & 7, l = g & 63;
    int krow = s * 32 + ((l >> 4) << 3);
    int col = t * 16 + (l & 15);
    half8 v;
#pragma unroll
    for (int j = 0; j < 8; ++j) v[j] = (_Float16)W1[(size_t)(krow + j) * 128 + col];
    *(half8*)&Wpk[(size_t)g * 8] = v;
}

// ---------------- layer1 GEMM via MFMA ----------------
__global__ __launch_bounds__(512) void gemm1_k(const float* __restrict__ x,
                                               const _Float16* __restrict__ Wpk,
                                               _Float16* __restrict__ h1, int Mt) {
    __shared__ __align__(16) _Float16 xs[32 * 256];   // 16 KB, XOR-swizzled
    const int t = threadIdx.x;
    const int l = t & 63;
    const int w = t >> 6;
    const int mstr = w >> 2;
    const int npair = w & 3;

    half8 bf0[8], bf1[8];
#pragma unroll
    for (int s = 0; s < 8; ++s) {
        bf0[s] = *(const half8*)&Wpk[(size_t)(((npair * 2 + 0) * 8 + s) * 64 + l) * 8];
        bf1[s] = *(const half8*)&Wpk[(size_t)(((npair * 2 + 1) * 8 + s) * 64 + l) * 8];
    }

    const int r = t >> 4;
    const int kc = t & 15;
    const int swz = (r & 7) << 4;
    const int arow = mstr * 16 + (l & 15);
    const int aswz = (arow & 7) << 4;
    const int abase = arow * 256;

    for (int mt = blockIdx.x; mt < Mt; mt += gridDim.x) {
        const int mBase = mt * 32;
        const float4* xrow = (const float4*)(x + (size_t)(mBase + r) * 256);
#pragma unroll
        for (int i = 0; i < 4; ++i) {
            float4 v = xrow[kc + i * 16];
            union { _Float16 h[4]; uint2 u; } cv;
            cv.h[0] = (_Float16)v.x; cv.h[1] = (_Float16)v.y;
            cv.h[2] = (_Float16)v.z; cv.h[3] = (_Float16)v.w;
            int kb = kc * 8 + i * 128;
            *(uint2*)&xs[r * 256 + ((kb ^ swz) >> 1)] = cv.u;
        }
        __syncthreads();
        f32x4 acc0 = {0.f, 0.f, 0.f, 0.f}, acc1 = {0.f, 0.f, 0.f, 0.f};
#pragma unroll
        for (int s = 0; s < 8; ++s) {
            int kb = s * 64 + ((l >> 4) << 4);
            half8 a = *(const half8*)&xs[abase + ((kb ^ aswz) >> 1)];
            acc0 = __builtin_amdgcn_mfma_f32_16x16x32_f16(a, bf0[s], acc0, 0, 0, 0);
            acc1 = __builtin_amdgcn_mfma_f32_16x16x32_f16(a, bf1[s], acc1, 0, 0, 0);
        }
        const int drow = mBase + mstr * 16 + ((l >> 4) << 2);
        const int dcol = npair * 32 + (l & 15);
#pragma unroll
        for (int rr = 0; rr < 4; ++rr) {
            h1[(size_t)(drow + rr) * 128 + dcol]      = (_Float16)acc0[rr];
            h1[(size_t)(drow + rr) * 128 + dcol + 16] = (_Float16)acc1[rr];
        }
        __syncthreads();
    }
}

// ---------------- layer1 attention coefficients [N,4] ----------------
__global__ void acoef1_k(const __half* __restrict__ h1, const float* __restrict__ att_s,
                         const float* __restrict__ att_d, float* __restrict__ a1s,
                         float* __restrict__ a1d, int Nn) {
    int g = blockIdx.x * 256 + threadIdx.x;
    if (g >= Nn * 4) return;
    int node = g >> 2, head = g & 3;
    const __half2* hp = (const __half2*)(h1 + (size_t)node * 128 + head * 32);
    const float* as = att_s + head * 32;
    const float* ad = att_d + head * 32;
    float s = 0.0f, d = 0.0f;
#pragma unroll
    for (int c = 0; c < 16; ++c) {
        float2 v = __half22float2(hp[c]);
        s += v.x * as[2 * c] + v.y * as[2 * c + 1];
        d += v.x * ad[2 * c] + v.y * ad[2 * c + 1];
    }
    a1s[g] = s; a1d[g] = d;
}

// ---------------- layer1 fused: softmax + aggregate + bias + ELU + gemm2 + acoef2 ----
__global__ __launch_bounds__(256) void agg1_k(const int* __restrict__ rowptr,
                                              const int* __restrict__ srcs,
                                              const float* __restrict__ a1s,
                                              const float* __restrict__ a1d,
                                              const __half* __restrict__ h1,
                                              const float* __restrict__ b1,
                                              const float* __restrict__ W2,
                                              const float* __restrict__ att_s2,
                                              const float* __restrict__ att_d2,
                                              __half* __restrict__ h2,
                                              float* __restrict__ a2s,
                                              float* __restrict__ a2d, int Nn) {
    __shared__ int   s_s[4][64];
    __shared__ float s_al[4][64][4];
    __shared__ float rowb[4][128];
    __shared__ float w2s[128 * 16];
    const int wv = threadIdx.x >> 6;
    const int lane = threadIdx.x & 63;
    const int n = blockIdx.x * 4 + wv;

    for (int i4 = threadIdx.x; i4 < 512; i4 += 256)
        *(float4*)&w2s[i4 * 4] = *(const float4*)&W2[i4 * 4];

    if (n < Nn) {
        const int beg = rowptr[n], end = rowptr[n + 1];
        const int cnt = end - beg;
        const float4 ad4 = ((const float4*)a1d)[n];

        int e = beg + lane;
        bool val = e < end;
        int sv = val ? srcs[e] : 0;
        float4 a = ((const float4*)a1s)[sv];
        float v0 = a.x + ad4.x, v1 = a.y + ad4.y, v2 = a.z + ad4.z, v3 = a.w + ad4.w;
        v0 = fmaxf(v0, LEAKY * v0); v1 = fmaxf(v1, LEAKY * v1);
        v2 = fmaxf(v2, LEAKY * v2); v3 = fmaxf(v3, LEAKY * v3);
        float al0 = val ? __expf(v0) : 0.0f, al1 = val ? __expf(v1) : 0.0f;
        float al2 = val ? __expf(v2) : 0.0f, al3 = val ? __expf(v3) : 0.0f;
        float t0 = al0, t1 = al1, t2 = al2, t3 = al3;
        for (int base = beg + 64; base < end; base += 64) {   // rare (deg>64)
            int ee = base + lane; bool vv = ee < end;
            int ss = vv ? srcs[ee] : 0;
            float4 aa = ((const float4*)a1s)[ss];
            float w0 = aa.x + ad4.x, w1 = aa.y + ad4.y, w2v = aa.z + ad4.z, w3 = aa.w + ad4.w;
            w0 = fmaxf(w0, LEAKY * w0); w1 = fmaxf(w1, LEAKY * w1);
            w2v = fmaxf(w2v, LEAKY * w2v); w3 = fmaxf(w3, LEAKY * w3);
            if (vv) { t0 += __expf(w0); t1 += __expf(w1); t2 += __expf(w2v); t3 += __expf(w3); }
        }
#pragma unroll
        for (int off = 1; off < 64; off <<= 1) {
            t0 += __shfl_xor(t0, off); t1 += __shfl_xor(t1, off);
            t2 += __shfl_xor(t2, off); t3 += __shfl_xor(t3, off);
        }
        const float i0 = 1.0f / (t0 + 1e-16f), i1 = 1.0f / (t1 + 1e-16f);
        const float i2 = 1.0f / (t2 + 1e-16f), i3 = 1.0f / (t3 + 1e-16f);

        const int hc = lane >> 4;
        float2 acc = make_float2(0.0f, 0.0f);
        const size_t lo = 2 * lane;

        s_s[wv][lane] = sv;
        s_al[wv][lane][0] = al0 * i0; s_al[wv][lane][1] = al1 * i1;
        s_al[wv][lane][2] = al2 * i2; s_al[wv][lane][3] = al3 * i3;
        int wcnt = cnt < 64 ? cnt : 64;
        int ko = 0;
        // 4-wide ILP: 4 independent h1-row gathers in flight
        for (; ko + 4 <= wcnt; ko += 4) {
            int s0 = s_s[wv][ko+0], s1 = s_s[wv][ko+1];
            int s2 = s_s[wv][ko+2], s3 = s_s[wv][ko+3];
            float p0 = s_al[wv][ko+0][hc], p1 = s_al[wv][ko+1][hc];
            float p2 = s_al[wv][ko+2][hc], p3 = s_al[wv][ko+3][hc];
            float2 g0 = __half22float2(*(const __half2*)&h1[(size_t)s0 * 128 + lo]);
            float2 g1 = __half22float2(*(const __half2*)&h1[(size_t)s1 * 128 + lo]);
            float2 g2 = __half22float2(*(const __half2*)&h1[(size_t)s2 * 128 + lo]);
            float2 g3 = __half22float2(*(const __half2*)&h1[(size_t)s3 * 128 + lo]);
            acc.x = fmaf(p0, g0.x, acc.x); acc.y = fmaf(p0, g0.y, acc.y);
            acc.x = fmaf(p1, g1.x, acc.x); acc.y = fmaf(p1, g1.y, acc.y);
            acc.x = fmaf(p2, g2.x, acc.x); acc.y = fmaf(p2, g2.y, acc.y);
            acc.x = fmaf(p3, g3.x, acc.x); acc.y = fmaf(p3, g3.y, acc.y);
        }
        for (; ko < wcnt; ++ko) {
            int s = s_s[wv][ko];
            float p = s_al[wv][ko][hc];
            float2 g = __half22float2(*(const __half2*)&h1[(size_t)s * 128 + lo]);
            acc.x = fmaf(p, g.x, acc.x); acc.y = fmaf(p, g.y, acc.y);
        }
        for (int base = beg + 64; base < end; base += 64) {   // rare
            int ee = base + lane; bool vv = ee < end;
            int ss = vv ? srcs[ee] : 0;
            float4 aa = ((const float4*)a1s)[ss];
            float w0 = aa.x + ad4.x, w1 = aa.y + ad4.y, w2v = aa.z + ad4.z, w3 = aa.w + ad4.w;
            w0 = fmaxf(w0, LEAKY * w0); w1 = fmaxf(w1, LEAKY * w1);
            w2v = fmaxf(w2v, LEAKY * w2v); w3 = fmaxf(w3, LEAKY * w3);
            s_s[wv][lane] = ss;
            s_al[wv][lane][0] = vv ? __expf(w0) * i0 : 0.0f;
            s_al[wv][lane][1] = vv ? __expf(w1) * i1 : 0.0f;
            s_al[wv][lane][2] = vv ? __expf(w2v) * i2 : 0.0f;
            s_al[wv][lane][3] = vv ? __expf(w3) * i3 : 0.0f;
            int wc = end - base; if (wc > 64) wc = 64;
            for (int k2 = 0; k2 < wc; ++k2) {
                int s = s_s[wv][k2];
                float p = s_al[wv][k2][hc];
                float2 g = __half22float2(*(const __half2*)&h1[(size_t)s * 128 + lo]);
                acc.x = fmaf(p, g.x, acc.x); acc.y = fmaf(p, g.y, acc.y);
            }
        }
        float2 bb = *(const float2*)&b1[2 * lane];
        float ox = acc.x + bb.x, oy = acc.y + bb.y;
        ox = ox > 0.0f ? ox : expm1f(ox);                 // ELU
        oy = oy > 0.0f ? oy : expm1f(oy);
        rowb[wv][2 * lane] = ox;
        rowb[wv][2 * lane + 1] = oy;
    }
    __syncthreads();
    if (n >= Nn) return;

    // fused layer2 GEMM row; k = kk*4+q ordering -> bank-conflict-free
    const int q = lane >> 4, j = lane & 15;
    const float* rb = rowb[wv];
    float part = 0.0f;
#pragma unroll
    for (int kk = 0; kk < 32; ++kk) {
        int k = kk * 4 + q;
        part = fmaf(rb[k], w2s[k * 16 + j], part);
    }
    part += __shfl_xor(part, 16);
    part += __shfl_xor(part, 32);
    float vs = part * att_s2[j];
    float vd = part * att_d2[j];
#pragma unroll
    for (int off = 1; off < 16; off <<= 1) {
        vs += __shfl_xor(vs, off);
        vd += __shfl_xor(vd, off);
    }
    if (lane < 16) h2[(size_t)n * 16 + j] = __float2half(part);
    if (lane == 0) { a2s[n] = vs; a2d[n] = vd; }
}

// ---------------- layer2 fused softmax + aggregate + bias ----------------
__global__ __launch_bounds__(256) void agg2_k(const int* __restrict__ rowptr,
                                              const int* __restrict__ srcs,
                                              const float* __restrict__ a2s,
                                              const float* __restrict__ a2d,
                                              const __half* __restrict__ h2,
                                              const float* __restrict__ b2,
                                              float* __restrict__ dout, int Nn) {
    __shared__ int   s_s[4][64];
    __shared__ float s_al[4][64];
    const int wv = threadIdx.x >> 6;
    const int lane = threadIdx.x & 63;
    const int n = blockIdx.x * 4 + wv;
    if (n >= Nn) return;
    const int beg = rowptr[n], end = rowptr[n + 1];
    const int cnt = end - beg;
    const float adn = a2d[n];

    int e = beg + lane;
    bool val = e < end;
    int sv = val ? srcs[e] : 0;
    float av = a2s[sv] + adn;
    av = fmaxf(av, LEAKY * av);
    float al = val ? __expf(av) : 0.0f;
    float ss = al;
    for (int base = beg + 64; base < end; base += 64) {
        int ee = base + lane; bool vv = ee < end;
        float aw = a2s[vv ? srcs[ee] : 0] + adn;
        aw = fmaxf(aw, LEAKY * aw);
        if (vv) ss += __expf(aw);
    }
#pragma unroll
    for (int off = 1; off < 64; off <<= 1) ss += __shfl_xor(ss, off);
    const float sinv = 1.0f / (ss + 1e-16f);

    const int eg = lane >> 4, j = lane & 15;
    float acc = 0.0f;
    s_s[wv][lane] = sv;
    s_al[wv][lane] = al * sinv;
    int wcnt = cnt < 64 ? cnt : 64;
    int ko = eg;
    for (; ko + 4 < wcnt; ko += 8) {        // 2-wide ILP per group
        int s0 = s_s[wv][ko], s1 = s_s[wv][ko + 4];
        float p0 = s_al[wv][ko], p1 = s_al[wv][ko + 4];
        float g0 = __half2float(h2[(size_t)s0 * 16 + j]);
        float g1 = __half2float(h2[(size_t)s1 * 16 + j]);
        acc = fmaf(p0, g0, acc);
        acc = fmaf(p1, g1, acc);
    }
    for (; ko < wcnt; ko += 4) {
        acc = fmaf(s_al[wv][ko], __half2float(h2[(size_t)s_s[wv][ko] * 16 + j]), acc);
    }
    for (int base = beg + 64; base < end; base += 64) {
        int ee = base + lane; bool vv = ee < end;
        int sn = vv ? srcs[ee] : 0;
        float aw = a2s[sn] + adn;
        aw = fmaxf(aw, LEAKY * aw);
        s_s[wv][lane] = sn;
        s_al[wv][lane] = vv ? __expf(aw) * sinv : 0.0f;
        int wc = end - base; if (wc > 64) wc = 64;
        for (int k2 = eg; k2 < wc; k2 += 4) {
            acc = fmaf(s_al[wv][k2], __half2float(h2[(size_t)s_s[wv][k2] * 16 + j]), acc);
        }
    }
    acc += __shfl_xor(acc, 16);
    acc += __shfl_xor(acc, 32);
    if (lane < 16) dout[(size_t)n * 16 + j] = acc + b2[j];
}

extern "C" void kernel_launch(void* const* d_in, const int* in_sizes, int n_in,
                              void* d_out, int out_size, void* d_ws, size_t ws_size,
                              hipStream_t stream) {
    const float* x      = (const float*)d_in[0];
    const int*   ei     = (const int*)d_in[1];
    const float* W1     = (const float*)d_in[2];
    const float* att_s1 = (const float*)d_in[3];
    const float* att_d1 = (const float*)d_in[4];
    const float* b1     = (const float*)d_in[5];
    const float* W2     = (const float*)d_in[6];
    const float* att_s2 = (const float*)d_in[7];
    const float* att_d2 = (const float*)d_in[8];
    const float* b2     = (const float*)d_in[9];
    float* dout = (float*)d_out;

    const int Nn = in_sizes[0] / 256;     // 100000
    const int E  = in_sizes[1] / 2;       // 1600000
    const int ET = E + Nn;

    char* p = (char*)d_ws;
    auto alloc = [&](size_t bytes) { char* r = p; p += (bytes + 255) & ~(size_t)255; return r; };
    _Float16* h1  = (_Float16*)alloc((size_t)Nn * 128 * 2);
    __half* h2    = (__half*)alloc((size_t)Nn * 16 * 2);
    _Float16* Wpk = (_Float16*)alloc(4096 * 8 * 2);
    float* a1s    = (float*)alloc((size_t)Nn * 4 * 4);
    float* a1d    = (float*)alloc((size_t)Nn * 4 * 4);
    float* a2s    = (float*)alloc((size_t)Nn * 4);
    float* a2d    = (float*)alloc((size_t)Nn * 4);
    int* rowptr   = (int*)alloc((size_t)(Nn + 1) * 4);
    int* cnt      = (int*)alloc((size_t)Nn * 4);
    int* cnt2     = (int*)alloc((size_t)Nn * 4);
    int* part     = (int*)alloc(128 * 4);
    int* srcs     = (int*)alloc((size_t)ET * 4);

    const int nbScan = (Nn + 1023) / 1024;

    // CSR build
    init_k<<<dim3((Nn + 255) / 256), dim3(256), 0, stream>>>(cnt, cnt2, Nn);
    hist_k<<<dim3((ET + 255) / 256), dim3(256), 0, stream>>>(ei, E, ET, cnt);
    scan_blk_k<<<dim3(nbScan), dim3(1024), 0, stream>>>(cnt, rowptr, part, Nn);
    scan_part_k<<<dim3(1), dim3(128), 0, stream>>>(part, nbScan);
    scan_add_k<<<dim3(nbScan), dim3(1024), 0, stream>>>(rowptr, part, Nn, ET);
    scatter_k<<<dim3((ET + 255) / 256), dim3(256), 0, stream>>>(ei, E, ET, rowptr, cnt2, srcs);
    // layer 1
    wpack1_k<<<dim3(16), dim3(256), 0, stream>>>(W1, Wpk);
    gemm1_k<<<dim3(512), dim3(512), 0, stream>>>(x, Wpk, h1, Nn / 32);
    acoef1_k<<<dim3((Nn * 4 + 255) / 256), dim3(256), 0, stream>>>((const __half*)h1, att_s1, att_d1, a1s, a1d, Nn);
    // fused agg1 + gemm2 + acoef2
    agg1_k<<<dim3((Nn + 3) / 4), dim3(256), 0, stream>>>(rowptr, srcs, a1s, a1d,
                                                         (const __half*)h1, b1,
                                                         W2, att_s2, att_d2,
                                                         h2, a2s, a2d, Nn);
    // layer 2 aggregation
    agg2_k<<<dim3((Nn + 3) / 4), dim3(256), 0, stream>>>(rowptr, srcs, a2s, a2d, h2, b2, dout, Nn);
}